// Round 1
// baseline (7233.008 us; speedup 1.0000x reference)
//
#include <hip/hip_runtime.h>
#include <math.h>

// Problem constants (from setup_inputs)
#define N_NODES 4096
#define BATCH   32
#define D_EMB   10
#define CIN     2
#define COUT    64
#define CI      66          // CIN + COUT
#define KSUP    3
#define NCOLS   2112        // BATCH * CI
#define LDV     2176        // NCOLS padded to 17*128 for the GEMM tiling

// ---------------------------------------------------------------------------
// P[n,m] = softmax_m( relu( E[n,:] . E[m,:] ) )   (row-wise softmax, axis=1)
// One block per row n; online (max,sum) then a second pass recomputes + stores.
// ---------------------------------------------------------------------------
__global__ __launch_bounds__(256) void k_softmax_p(const float* __restrict__ E,
                                                   float* __restrict__ P) {
  const int n = blockIdx.x;
  const int tid = threadIdx.x;
  __shared__ float En[D_EMB];
  __shared__ float ms[256], ss[256];
  if (tid < D_EMB) En[tid] = E[n * D_EMB + tid];
  __syncthreads();
  float en[D_EMB];
#pragma unroll
  for (int d = 0; d < D_EMB; ++d) en[d] = En[d];

  float m = -1e30f, s = 0.f;
  for (int c = tid; c < N_NODES; c += 256) {
    const float* Ec = E + c * D_EMB;
    float v = 0.f;
#pragma unroll
    for (int d = 0; d < D_EMB; ++d) v += en[d] * Ec[d];
    v = fmaxf(v, 0.f);
    if (v > m) { s *= __expf(m - v); m = v; }
    s += __expf(v - m);
  }
  ms[tid] = m; ss[tid] = s;
  __syncthreads();
  for (int off = 128; off > 0; off >>= 1) {
    if (tid < off) {
      float m2 = ms[tid + off], s2 = ss[tid + off];
      float m1 = ms[tid], s1 = ss[tid];
      float mm = fmaxf(m1, m2);
      ms[tid] = mm;
      ss[tid] = s1 * __expf(m1 - mm) + s2 * __expf(m2 - mm);
    }
    __syncthreads();
  }
  const float M = ms[0];
  const float inv = 1.f / ss[0];
  float* Pr = P + (size_t)n * N_NODES;
  for (int c = tid; c < N_NODES; c += 256) {
    const float* Ec = E + c * D_EMB;
    float v = 0.f;
#pragma unroll
    for (int d = 0; d < D_EMB; ++d) v += en[d] * Ec[d];
    v = fmaxf(v, 0.f);
    Pr[c] = __expf(v - M) * inv;
  }
}

// ---------------------------------------------------------------------------
// V0[m, b*CI+c] = (c<CIN) ? X[b,m,c] : H[b,m,c-CIN]; also writes the X part of C.
// ---------------------------------------------------------------------------
__global__ __launch_bounds__(256) void k_build_v0(const float* __restrict__ X,
                                                  const float* __restrict__ H,
                                                  float* __restrict__ V0,
                                                  float* __restrict__ Cb) {
  size_t idx = (size_t)blockIdx.x * 256 + threadIdx.x;
  if (idx >= (size_t)N_NODES * NCOLS) return;
  const int m = (int)(idx / NCOLS);
  const int col = (int)(idx % NCOLS);
  const int b = col / CI;
  const int c = col % CI;
  float v;
  if (c < CIN) v = X[((size_t)b * N_NODES + m) * CIN + c];
  else         v = H[((size_t)b * N_NODES + m) * COUT + (c - CIN)];
  V0[(size_t)m * LDV + col] = v;
  if (c < CIN) Cb[(size_t)m * LDV + col] = v;
}

// ---------------------------------------------------------------------------
// fp32 GEMM: C[M x LDV] = A[M x N_NODES] * B[N_NODES x LDV]
// 128x128 block tile, BK=8, 8x8 per thread (256 threads).
// ---------------------------------------------------------------------------
#define BM 128
#define BN 128
#define BK 8
__global__ __launch_bounds__(256) void k_gemm(const float* __restrict__ A,
                                              const float* __restrict__ B,
                                              float* __restrict__ C) {
  __shared__ __align__(16) float As[BK][BM + 4];  // +4 pad: conflict-free, keeps 16B align
  __shared__ __align__(16) float Bs[BK][BN];
  const int tid = threadIdx.x;
  const int cb = blockIdx.x * BN;
  const int rb = blockIdx.y * BM;
  const int tm = tid >> 4;    // 0..15
  const int tn = tid & 15;    // 0..15

  float acc[8][8] = {};

  for (int k0 = 0; k0 < N_NODES; k0 += BK) {
#pragma unroll
    for (int j = 0; j < 4; ++j) {
      const int e = tid + j * 256;       // 0..1023
      const int r = e >> 3;              // 0..127
      const int c = e & 7;               // 0..7
      As[c][r] = A[(size_t)(rb + r) * N_NODES + k0 + c];
    }
    {
      const int r = tid >> 5;            // 0..7
      const int c4 = (tid & 31) * 4;     // 0..124
      *(float4*)&Bs[r][c4] = *(const float4*)&B[(size_t)(k0 + r) * LDV + cb + c4];
    }
    __syncthreads();
#pragma unroll
    for (int kk = 0; kk < BK; ++kk) {
      const float4 a0 = *(const float4*)&As[kk][tm * 8];
      const float4 a1 = *(const float4*)&As[kk][tm * 8 + 4];
      const float4 b0 = *(const float4*)&Bs[kk][tn * 8];
      const float4 b1 = *(const float4*)&Bs[kk][tn * 8 + 4];
      const float av[8] = {a0.x, a0.y, a0.z, a0.w, a1.x, a1.y, a1.z, a1.w};
      const float bv[8] = {b0.x, b0.y, b0.z, b0.w, b1.x, b1.y, b1.z, b1.w};
#pragma unroll
      for (int i = 0; i < 8; ++i)
#pragma unroll
        for (int j = 0; j < 8; ++j)
          acc[i][j] += av[i] * bv[j];
    }
    __syncthreads();
  }

#pragma unroll
  for (int i = 0; i < 8; ++i) {
    const int row = rb + tm * 8 + i;
    float4 v0 = {acc[i][0], acc[i][1], acc[i][2], acc[i][3]};
    float4 v1 = {acc[i][4], acc[i][5], acc[i][6], acc[i][7]};
    *(float4*)&C[(size_t)row * LDV + cb + tn * 8]     = v0;
    *(float4*)&C[(size_t)row * LDV + cb + tn * 8 + 4] = v1;
  }
}

// ---------------------------------------------------------------------------
// Gate transform: per node n and output-chunk ch (32 of 128 outputs):
//   W[n,k,i,o] = sum_d E[n,d] Wg[d,k,i,o];  bias[n,o] = sum_d E[n,d] bg[d,o]
//   ZR[b,n,o]  = sigmoid( sum_{k,i} XG[b,n,k,i] W[n,k,i,o] + bias )
//   XG0 = V0 row, XG1 = G1 row, XG2 = 2*G2 - V0 row
//   o<64 -> Z: write Cb[n, b*CI + CIN + o] = Z * H[b,n,o]
//   o>=64 -> R[b,n,o-64]
// ---------------------------------------------------------------------------
__global__ __launch_bounds__(256) void k_gate(const float* __restrict__ V0,
                                              const float* __restrict__ G1,
                                              const float* __restrict__ G2,
                                              const float* __restrict__ E,
                                              const float* __restrict__ Wg,
                                              const float* __restrict__ bg,
                                              const float* __restrict__ H,
                                              float* __restrict__ Cb,
                                              float* __restrict__ R) {
  const int n = blockIdx.y;
  const int ch = blockIdx.x;     // 0..3
  const int tid = threadIdx.x;
  __shared__ float En[D_EMB];
  __shared__ float bo[32];
  __shared__ __align__(16) float Wch[KSUP * CI * 32];
  __shared__ float xg[3][NCOLS];

  if (tid < D_EMB) En[tid] = E[n * D_EMB + tid];
  __syncthreads();

  if (tid < 32) {
    float a = 0.f;
#pragma unroll
    for (int d = 0; d < D_EMB; ++d) a += En[d] * bg[d * 128 + ch * 32 + tid];
    bo[tid] = a;
  }
  for (int idx = tid; idx < KSUP * CI * 32; idx += 256) {
    const int k = idx / (CI * 32);
    const int rem = idx - k * (CI * 32);
    const int i = rem >> 5;
    const int o = rem & 31;
    float a = 0.f;
#pragma unroll
    for (int d = 0; d < D_EMB; ++d)
      a += En[d] * Wg[(((size_t)d * KSUP + k) * CI + i) * 128 + ch * 32 + o];
    Wch[idx] = a;
  }
  {
    const float* v0r = V0 + (size_t)n * LDV;
    const float* g1r = G1 + (size_t)n * LDV;
    const float* g2r = G2 + (size_t)n * LDV;
    for (int idx = tid; idx < NCOLS; idx += 256) {
      const float a0 = v0r[idx];
      xg[0][idx] = a0;
      xg[1][idx] = g1r[idx];
      xg[2][idx] = 2.f * g2r[idx] - a0;
    }
  }
  __syncthreads();

  const int b = tid >> 3;          // 0..31
  const int ob = (tid & 7) * 4;    // 0,4,...,28
  float a0 = bo[ob], a1 = bo[ob + 1], a2 = bo[ob + 2], a3 = bo[ob + 3];
#pragma unroll
  for (int k = 0; k < KSUP; ++k) {
    const float* xr = &xg[k][b * CI];
    const float* wr = &Wch[k * CI * 32 + ob];
    for (int i = 0; i < CI; ++i) {
      const float xv = xr[i];
      const float4 wv = *(const float4*)&wr[i * 32];
      a0 += xv * wv.x; a1 += xv * wv.y; a2 += xv * wv.z; a3 += xv * wv.w;
    }
  }
  float4 sg;
  sg.x = 1.f / (1.f + __expf(-a0));
  sg.y = 1.f / (1.f + __expf(-a1));
  sg.z = 1.f / (1.f + __expf(-a2));
  sg.w = 1.f / (1.f + __expf(-a3));
  const int og = ch * 32 + ob;
  if (og < COUT) {  // Z chunk
    const float4 h = *(const float4*)&H[((size_t)b * N_NODES + n) * COUT + og];
    float* cp = &Cb[(size_t)n * LDV + b * CI + CIN + og];
    cp[0] = sg.x * h.x; cp[1] = sg.y * h.y; cp[2] = sg.z * h.z; cp[3] = sg.w * h.w;
  } else {          // R chunk
    *(float4*)&R[((size_t)b * N_NODES + n) * COUT + (og - COUT)] = sg;
  }
}

// ---------------------------------------------------------------------------
// Update transform + final gating:
//   HC = tanh( sum_{k,i} XGc[b,n,k,i] Wn[k,i,o] + bias )
//   out = R*H + (1-R)*HC
// ---------------------------------------------------------------------------
__global__ __launch_bounds__(256) void k_update(const float* __restrict__ Cb,
                                                const float* __restrict__ G1,
                                                const float* __restrict__ G2,
                                                const float* __restrict__ E,
                                                const float* __restrict__ Wu,
                                                const float* __restrict__ bu,
                                                const float* __restrict__ H,
                                                const float* __restrict__ R,
                                                float* __restrict__ Out) {
  const int n = blockIdx.y;
  const int ch = blockIdx.x;     // 0..1
  const int tid = threadIdx.x;
  __shared__ float En[D_EMB];
  __shared__ float bo[32];
  __shared__ __align__(16) float Wch[KSUP * CI * 32];
  __shared__ float xg[3][NCOLS];

  if (tid < D_EMB) En[tid] = E[n * D_EMB + tid];
  __syncthreads();

  if (tid < 32) {
    float a = 0.f;
#pragma unroll
    for (int d = 0; d < D_EMB; ++d) a += En[d] * bu[d * COUT + ch * 32 + tid];
    bo[tid] = a;
  }
  for (int idx = tid; idx < KSUP * CI * 32; idx += 256) {
    const int k = idx / (CI * 32);
    const int rem = idx - k * (CI * 32);
    const int i = rem >> 5;
    const int o = rem & 31;
    float a = 0.f;
#pragma unroll
    for (int d = 0; d < D_EMB; ++d)
      a += En[d] * Wu[(((size_t)d * KSUP + k) * CI + i) * COUT + ch * 32 + o];
    Wch[idx] = a;
  }
  {
    const float* v0r = Cb + (size_t)n * LDV;
    const float* g1r = G1 + (size_t)n * LDV;
    const float* g2r = G2 + (size_t)n * LDV;
    for (int idx = tid; idx < NCOLS; idx += 256) {
      const float a0 = v0r[idx];
      xg[0][idx] = a0;
      xg[1][idx] = g1r[idx];
      xg[2][idx] = 2.f * g2r[idx] - a0;
    }
  }
  __syncthreads();

  const int b = tid >> 3;          // 0..31
  const int ob = (tid & 7) * 4;    // 0,4,...,28
  float a0 = bo[ob], a1 = bo[ob + 1], a2 = bo[ob + 2], a3 = bo[ob + 3];
#pragma unroll
  for (int k = 0; k < KSUP; ++k) {
    const float* xr = &xg[k][b * CI];
    const float* wr = &Wch[k * CI * 32 + ob];
    for (int i = 0; i < CI; ++i) {
      const float xv = xr[i];
      const float4 wv = *(const float4*)&wr[i * 32];
      a0 += xv * wv.x; a1 += xv * wv.y; a2 += xv * wv.z; a3 += xv * wv.w;
    }
  }
  const int og = ch * 32 + ob;
  const size_t base = ((size_t)b * N_NODES + n) * COUT + og;
  const float4 h = *(const float4*)&H[base];
  const float4 r = *(const float4*)&R[base];
  float4 o;
  o.x = r.x * h.x + (1.f - r.x) * tanhf(a0);
  o.y = r.y * h.y + (1.f - r.y) * tanhf(a1);
  o.z = r.z * h.z + (1.f - r.z) * tanhf(a2);
  o.w = r.w * h.w + (1.f - r.w) * tanhf(a3);
  *(float4*)&Out[base] = o;
}

// ---------------------------------------------------------------------------
extern "C" void kernel_launch(void* const* d_in, const int* in_sizes, int n_in,
                              void* d_out, int out_size, void* d_ws, size_t ws_size,
                              hipStream_t stream) {
  const float* X  = (const float*)d_in[0];
  const float* H  = (const float*)d_in[1];
  const float* E  = (const float*)d_in[2];
  const float* Wg = (const float*)d_in[3];
  const float* bg = (const float*)d_in[4];
  const float* Wu = (const float*)d_in[5];
  const float* bu = (const float*)d_in[6];
  float* out = (float*)d_out;

  // Workspace layout (floats): total ~60.8M floats = ~243 MB
  float* ws = (float*)d_ws;
  float* P  = ws;                                  // N*N          = 16,777,216
  float* V0 = P  + (size_t)N_NODES * N_NODES;      // N*LDV        =  8,912,896
  float* G1 = V0 + (size_t)N_NODES * LDV;
  float* G2 = G1 + (size_t)N_NODES * LDV;
  float* Cb = G2 + (size_t)N_NODES * LDV;
  float* R  = Cb + (size_t)N_NODES * LDV;          // B*N*COUT     =  8,388,608

  // 1. adjacency
  k_softmax_p<<<N_NODES, 256, 0, stream>>>(E, P);
  // 2. V0 = concat(X,H) in [m, b*CI+c] layout (+ X part of C)
  {
    const size_t tot = (size_t)N_NODES * NCOLS;
    k_build_v0<<<(int)((tot + 255) / 256), 256, 0, stream>>>(X, H, V0, Cb);
  }
  dim3 gg(LDV / BN, N_NODES / BM);
  // 3. gate propagation: G1 = P V0, G2 = P G1
  k_gemm<<<gg, 256, 0, stream>>>(P, V0, G1);
  k_gemm<<<gg, 256, 0, stream>>>(P, G1, G2);
  // 4. gate transform -> Cb (Z*H part), R
  k_gate<<<dim3(4, N_NODES), 256, 0, stream>>>(V0, G1, G2, E, Wg, bg, H, Cb, R);
  // 5. update propagation: G1 = P C, G2 = P G1
  k_gemm<<<gg, 256, 0, stream>>>(P, Cb, G1);
  k_gemm<<<gg, 256, 0, stream>>>(P, G1, G2);
  // 6. update transform + final gating -> out
  k_update<<<dim3(2, N_NODES), 256, 0, stream>>>(Cb, G1, G2, E, Wu, bu, H, R, out);
}

// Round 2
// 5167.896 us; speedup vs baseline: 1.3996x; 1.3996x over previous
//
#include <hip/hip_runtime.h>
#include <math.h>

// Problem constants (from setup_inputs)
#define N_NODES 4096
#define BATCH   32
#define D_EMB   10
#define CIN     2
#define COUT    64
#define CI      66          // CIN + COUT
#define KSUP    3
#define NCOLS   2112        // BATCH * CI
#define LDV     2176        // NCOLS padded to 17*128 for the GEMM tiling
#define OCH     16          // outputs per transform block chunk

// ---------------------------------------------------------------------------
// P[n,m] = softmax_m( relu( E[n,:] . E[m,:] ) )   (row-wise softmax, axis=1)
// ---------------------------------------------------------------------------
__global__ __launch_bounds__(256) void k_softmax_p(const float* __restrict__ E,
                                                   float* __restrict__ P) {
  const int n = blockIdx.x;
  const int tid = threadIdx.x;
  __shared__ float En[D_EMB];
  __shared__ float ms[256], ss[256];
  if (tid < D_EMB) En[tid] = E[n * D_EMB + tid];
  __syncthreads();
  float en[D_EMB];
#pragma unroll
  for (int d = 0; d < D_EMB; ++d) en[d] = En[d];

  float m = -1e30f, s = 0.f;
  for (int c = tid; c < N_NODES; c += 256) {
    const float* Ec = E + c * D_EMB;
    float v = 0.f;
#pragma unroll
    for (int d = 0; d < D_EMB; ++d) v += en[d] * Ec[d];
    v = fmaxf(v, 0.f);
    if (v > m) { s *= __expf(m - v); m = v; }
    s += __expf(v - m);
  }
  ms[tid] = m; ss[tid] = s;
  __syncthreads();
  for (int off = 128; off > 0; off >>= 1) {
    if (tid < off) {
      float m2 = ms[tid + off], s2 = ss[tid + off];
      float m1 = ms[tid], s1 = ss[tid];
      float mm = fmaxf(m1, m2);
      ms[tid] = mm;
      ss[tid] = s1 * __expf(m1 - mm) + s2 * __expf(m2 - mm);
    }
    __syncthreads();
  }
  const float M = ms[0];
  const float inv = 1.f / ss[0];
  float* Pr = P + (size_t)n * N_NODES;
  for (int c = tid; c < N_NODES; c += 256) {
    const float* Ec = E + c * D_EMB;
    float v = 0.f;
#pragma unroll
    for (int d = 0; d < D_EMB; ++d) v += en[d] * Ec[d];
    v = fmaxf(v, 0.f);
    Pr[c] = __expf(v - M) * inv;
  }
}

// ---------------------------------------------------------------------------
// V0[m, b*CI+c] = (c<CIN) ? X[b,m,c] : H[b,m,c-CIN]; also writes the X part of C.
// ---------------------------------------------------------------------------
__global__ __launch_bounds__(256) void k_build_v0(const float* __restrict__ X,
                                                  const float* __restrict__ H,
                                                  float* __restrict__ V0,
                                                  float* __restrict__ Cb) {
  size_t idx = (size_t)blockIdx.x * 256 + threadIdx.x;
  if (idx >= (size_t)N_NODES * NCOLS) return;
  const int m = (int)(idx / NCOLS);
  const int col = (int)(idx % NCOLS);
  const int b = col / CI;
  const int c = col % CI;
  float v;
  if (c < CIN) v = X[((size_t)b * N_NODES + m) * CIN + c];
  else         v = H[((size_t)b * N_NODES + m) * COUT + (c - CIN)];
  V0[(size_t)m * LDV + col] = v;
  if (c < CIN) Cb[(size_t)m * LDV + col] = v;
}

// ---------------------------------------------------------------------------
// fp32 GEMM: C[M x LDV] = A[M x N_NODES] * B[N_NODES x LDV]
// 128x128 block tile, BK=8, 8x8 per thread (256 threads).
// ---------------------------------------------------------------------------
#define BM 128
#define BN 128
#define BK 8
__global__ __launch_bounds__(256) void k_gemm(const float* __restrict__ A,
                                              const float* __restrict__ B,
                                              float* __restrict__ C) {
  __shared__ __align__(16) float As[BK][BM + 4];
  __shared__ __align__(16) float Bs[BK][BN];
  const int tid = threadIdx.x;
  const int cb = blockIdx.x * BN;
  const int rb = blockIdx.y * BM;
  const int tm = tid >> 4;    // 0..15
  const int tn = tid & 15;    // 0..15

  float acc[8][8] = {};

  for (int k0 = 0; k0 < N_NODES; k0 += BK) {
#pragma unroll
    for (int j = 0; j < 4; ++j) {
      const int e = tid + j * 256;       // 0..1023
      const int r = e >> 3;              // 0..127
      const int c = e & 7;               // 0..7
      As[c][r] = A[(size_t)(rb + r) * N_NODES + k0 + c];
    }
    {
      const int r = tid >> 5;            // 0..7
      const int c4 = (tid & 31) * 4;     // 0..124
      *(float4*)&Bs[r][c4] = *(const float4*)&B[(size_t)(k0 + r) * LDV + cb + c4];
    }
    __syncthreads();
#pragma unroll
    for (int kk = 0; kk < BK; ++kk) {
      const float4 a0 = *(const float4*)&As[kk][tm * 8];
      const float4 a1 = *(const float4*)&As[kk][tm * 8 + 4];
      const float4 b0 = *(const float4*)&Bs[kk][tn * 8];
      const float4 b1 = *(const float4*)&Bs[kk][tn * 8 + 4];
      const float av[8] = {a0.x, a0.y, a0.z, a0.w, a1.x, a1.y, a1.z, a1.w};
      const float bv[8] = {b0.x, b0.y, b0.z, b0.w, b1.x, b1.y, b1.z, b1.w};
#pragma unroll
      for (int i = 0; i < 8; ++i)
#pragma unroll
        for (int j = 0; j < 8; ++j)
          acc[i][j] += av[i] * bv[j];
    }
    __syncthreads();
  }

#pragma unroll
  for (int i = 0; i < 8; ++i) {
    const int row = rb + tm * 8 + i;
    float4 v0 = {acc[i][0], acc[i][1], acc[i][2], acc[i][3]};
    float4 v1 = {acc[i][4], acc[i][5], acc[i][6], acc[i][7]};
    *(float4*)&C[(size_t)row * LDV + cb + tn * 8]     = v0;
    *(float4*)&C[(size_t)row * LDV + cb + tn * 8 + 4] = v1;
  }
}

__device__ __forceinline__ float fast_sigmoid(float x) {
  return 1.f / (1.f + __expf(-x));
}
__device__ __forceinline__ float fast_tanh(float x) {
  // tanh(x) = 1 - 2/(exp(2x)+1); __expf(inf)->inf gives correct saturation
  return 1.f - 2.f / (__expf(2.f * x) + 1.f);
}

// ---------------------------------------------------------------------------
// Gate transform. Block = (node n, chunk of OCH=16 of the 128 outputs).
// Wch[k,i,o] = sum_d E[n,d] Wg[d,k,i, ch*16+o]  staged in LDS (12.7 KB)
// xg[k][b*CI+i] staged in LDS (25.3 KB)
// Each thread: b = tid>>3, two outputs o2 = (tid&7)*2 (+1).
// VGPR discipline: __launch_bounds__(256,4) -> <=128 VGPRs, bounded unrolls.
// ---------------------------------------------------------------------------
__global__ __launch_bounds__(256, 4) void k_gate(const float* __restrict__ V0,
                                                 const float* __restrict__ G1,
                                                 const float* __restrict__ G2,
                                                 const float* __restrict__ E,
                                                 const float* __restrict__ Wg,
                                                 const float* __restrict__ bg,
                                                 const float* __restrict__ H,
                                                 float* __restrict__ Cb,
                                                 float* __restrict__ R) {
  const int n = blockIdx.y;
  const int ch = blockIdx.x;     // 0..7 (chunks of 16 of 128 outputs)
  const int tid = threadIdx.x;
  __shared__ float En[D_EMB];
  __shared__ float bo[OCH];
  __shared__ __align__(16) float Wch[KSUP * CI * OCH];   // 12672 B
  __shared__ float xg[3][NCOLS];                         // 25344 B

  if (tid < D_EMB) En[tid] = E[n * D_EMB + tid];
  __syncthreads();

  if (tid < OCH) {
    float a = 0.f;
#pragma unroll
    for (int d = 0; d < D_EMB; ++d) a += En[d] * bg[d * 128 + ch * OCH + tid];
    bo[tid] = a;
  }
  for (int idx = tid; idx < KSUP * CI * OCH; idx += 256) {
    const int k = idx / (CI * OCH);
    const int rem = idx - k * (CI * OCH);
    const int i = rem >> 4;
    const int o = rem & (OCH - 1);
    float a = 0.f;
#pragma unroll
    for (int d = 0; d < D_EMB; ++d)
      a += En[d] * Wg[(((size_t)d * KSUP + k) * CI + i) * 128 + ch * OCH + o];
    Wch[idx] = a;
  }
  {
    const float* v0r = V0 + (size_t)n * LDV;
    const float* g1r = G1 + (size_t)n * LDV;
    const float* g2r = G2 + (size_t)n * LDV;
    for (int idx = tid; idx < NCOLS; idx += 256) {
      const float a0 = v0r[idx];
      xg[0][idx] = a0;
      xg[1][idx] = g1r[idx];
      xg[2][idx] = 2.f * g2r[idx] - a0;
    }
  }
  __syncthreads();

  const int b = tid >> 3;          // 0..31
  const int o2 = (tid & 7) * 2;    // 0,2,...,14
  float a0 = bo[o2], a1 = bo[o2 + 1];
#pragma unroll 1
  for (int k = 0; k < KSUP; ++k) {
    const float* xr = &xg[k][b * CI];
    const float* wr = &Wch[k * CI * OCH + o2];
#pragma unroll 4
    for (int i = 0; i < CI; ++i) {
      const float xv = xr[i];
      const float2 wv = *(const float2*)&wr[i * OCH];
      a0 += xv * wv.x;
      a1 += xv * wv.y;
    }
  }
  const float s0 = fast_sigmoid(a0);
  const float s1 = fast_sigmoid(a1);
  const int og = ch * OCH + o2;
  if (og < COUT) {  // Z chunk: Cb[n, b*CI + CIN + og] = Z * H
    const float2 h = *(const float2*)&H[((size_t)b * N_NODES + n) * COUT + og];
    float2 zh = {s0 * h.x, s1 * h.y};
    *(float2*)&Cb[(size_t)n * LDV + b * CI + CIN + og] = zh;
  } else {          // R chunk
    float2 r = {s0, s1};
    *(float2*)&R[((size_t)b * N_NODES + n) * COUT + (og - COUT)] = r;
  }
}

// ---------------------------------------------------------------------------
// Update transform + final gating. Block = (node n, chunk of 16 of 64 outputs).
// ---------------------------------------------------------------------------
__global__ __launch_bounds__(256, 4) void k_update(const float* __restrict__ Cb,
                                                   const float* __restrict__ G1,
                                                   const float* __restrict__ G2,
                                                   const float* __restrict__ E,
                                                   const float* __restrict__ Wu,
                                                   const float* __restrict__ bu,
                                                   const float* __restrict__ H,
                                                   const float* __restrict__ R,
                                                   float* __restrict__ Out) {
  const int n = blockIdx.y;
  const int ch = blockIdx.x;     // 0..3
  const int tid = threadIdx.x;
  __shared__ float En[D_EMB];
  __shared__ float bo[OCH];
  __shared__ __align__(16) float Wch[KSUP * CI * OCH];
  __shared__ float xg[3][NCOLS];

  if (tid < D_EMB) En[tid] = E[n * D_EMB + tid];
  __syncthreads();

  if (tid < OCH) {
    float a = 0.f;
#pragma unroll
    for (int d = 0; d < D_EMB; ++d) a += En[d] * bu[d * COUT + ch * OCH + tid];
    bo[tid] = a;
  }
  for (int idx = tid; idx < KSUP * CI * OCH; idx += 256) {
    const int k = idx / (CI * OCH);
    const int rem = idx - k * (CI * OCH);
    const int i = rem >> 4;
    const int o = rem & (OCH - 1);
    float a = 0.f;
#pragma unroll
    for (int d = 0; d < D_EMB; ++d)
      a += En[d] * Wu[(((size_t)d * KSUP + k) * CI + i) * COUT + ch * OCH + o];
    Wch[idx] = a;
  }
  {
    const float* v0r = Cb + (size_t)n * LDV;
    const float* g1r = G1 + (size_t)n * LDV;
    const float* g2r = G2 + (size_t)n * LDV;
    for (int idx = tid; idx < NCOLS; idx += 256) {
      const float a0 = v0r[idx];
      xg[0][idx] = a0;
      xg[1][idx] = g1r[idx];
      xg[2][idx] = 2.f * g2r[idx] - a0;
    }
  }
  __syncthreads();

  const int b = tid >> 3;          // 0..31
  const int o2 = (tid & 7) * 2;    // 0..14
  float a0 = bo[o2], a1 = bo[o2 + 1];
#pragma unroll 1
  for (int k = 0; k < KSUP; ++k) {
    const float* xr = &xg[k][b * CI];
    const float* wr = &Wch[k * CI * OCH + o2];
#pragma unroll 4
    for (int i = 0; i < CI; ++i) {
      const float xv = xr[i];
      const float2 wv = *(const float2*)&wr[i * OCH];
      a0 += xv * wv.x;
      a1 += xv * wv.y;
    }
  }
  const int og = ch * OCH + o2;
  const size_t base = ((size_t)b * N_NODES + n) * COUT + og;
  const float2 h = *(const float2*)&H[base];
  const float2 r = *(const float2*)&R[base];
  float2 o;
  o.x = r.x * h.x + (1.f - r.x) * fast_tanh(a0);
  o.y = r.y * h.y + (1.f - r.y) * fast_tanh(a1);
  *(float2*)&Out[base] = o;
}

// ---------------------------------------------------------------------------
extern "C" void kernel_launch(void* const* d_in, const int* in_sizes, int n_in,
                              void* d_out, int out_size, void* d_ws, size_t ws_size,
                              hipStream_t stream) {
  const float* X  = (const float*)d_in[0];
  const float* H  = (const float*)d_in[1];
  const float* E  = (const float*)d_in[2];
  const float* Wg = (const float*)d_in[3];
  const float* bg = (const float*)d_in[4];
  const float* Wu = (const float*)d_in[5];
  const float* bu = (const float*)d_in[6];
  float* out = (float*)d_out;

  float* ws = (float*)d_ws;
  float* P  = ws;                                  // N*N          = 16,777,216
  float* V0 = P  + (size_t)N_NODES * N_NODES;      // N*LDV        =  8,912,896
  float* G1 = V0 + (size_t)N_NODES * LDV;
  float* G2 = G1 + (size_t)N_NODES * LDV;
  float* Cb = G2 + (size_t)N_NODES * LDV;
  float* R  = Cb + (size_t)N_NODES * LDV;          // B*N*COUT     =  8,388,608

  // 1. adjacency
  k_softmax_p<<<N_NODES, 256, 0, stream>>>(E, P);
  // 2. V0 = concat(X,H) in [m, b*CI+c] layout (+ X part of C)
  {
    const size_t tot = (size_t)N_NODES * NCOLS;
    k_build_v0<<<(int)((tot + 255) / 256), 256, 0, stream>>>(X, H, V0, Cb);
  }
  dim3 gg(LDV / BN, N_NODES / BM);
  // 3. gate propagation: G1 = P V0, G2 = P G1
  k_gemm<<<gg, 256, 0, stream>>>(P, V0, G1);
  k_gemm<<<gg, 256, 0, stream>>>(P, G1, G2);
  // 4. gate transform -> Cb (Z*H part), R
  k_gate<<<dim3(128 / OCH, N_NODES), 256, 0, stream>>>(V0, G1, G2, E, Wg, bg, H, Cb, R);
  // 5. update propagation: G1 = P C, G2 = P G1
  k_gemm<<<gg, 256, 0, stream>>>(P, Cb, G1);
  k_gemm<<<gg, 256, 0, stream>>>(P, G1, G2);
  // 6. update transform + final gating -> out
  k_update<<<dim3(COUT / OCH, N_NODES), 256, 0, stream>>>(Cb, G1, G2, E, Wu, bu, H, R, out);
}

// Round 4
// 1427.710 us; speedup vs baseline: 5.0662x; 3.6197x over previous
//
#include <hip/hip_runtime.h>
#include <math.h>

// Problem constants (from setup_inputs)
#define N_NODES 4096
#define BATCH   32
#define D_EMB   10
#define CIN     2
#define COUT    64
#define CI      66          // CIN + COUT
#define KSUP    3
#define NCOLS   2112        // BATCH * CI
#define NPAD    2176        // NCOLS padded to 17*128 tiles
#define LDT     4096        // t-layout row stride (m contiguous)
#define OCH     16          // outputs per transform block chunk

// fp16 everywhere in the GEMM path: same MFMA rate as bf16, 8x less rounding
// error (2^-11 vs 2^-8 RNE). All values |.| <= ~10 (H=0 at setup) -> no overflow.
typedef _Float16 half_t;
typedef __attribute__((ext_vector_type(8))) _Float16 f16x8;
typedef __attribute__((ext_vector_type(4))) float f32x4;

__device__ __forceinline__ float fast_sigmoid(float x) { return 1.f / (1.f + __expf(-x)); }
__device__ __forceinline__ float fast_tanh(float x) { return 1.f - 2.f / (__expf(2.f * x) + 1.f); }

__device__ __forceinline__ void gld_lds16(const half_t* g, half_t* l) {
  __builtin_amdgcn_global_load_lds(
      (const __attribute__((address_space(1))) void*)g,
      (__attribute__((address_space(3))) void*)l, 16, 0, 0);
}

// ---------------------------------------------------------------------------
// P[n,m] = softmax_m(relu(E[n,:].E[m,:])) stored directly as fp16.
// ---------------------------------------------------------------------------
__global__ __launch_bounds__(256) void k_softmax_p(const float* __restrict__ E,
                                                   half_t* __restrict__ Pb) {
  const int n = blockIdx.x;
  const int tid = threadIdx.x;
  __shared__ float En[D_EMB];
  __shared__ float ms[256], ss[256];
  if (tid < D_EMB) En[tid] = E[n * D_EMB + tid];
  __syncthreads();
  float en[D_EMB];
#pragma unroll
  for (int d = 0; d < D_EMB; ++d) en[d] = En[d];

  float m = -1e30f, s = 0.f;
  for (int c = tid; c < N_NODES; c += 256) {
    const float* Ec = E + c * D_EMB;
    float v = 0.f;
#pragma unroll
    for (int d = 0; d < D_EMB; ++d) v += en[d] * Ec[d];
    v = fmaxf(v, 0.f);
    if (v > m) { s *= __expf(m - v); m = v; }
    s += __expf(v - m);
  }
  ms[tid] = m; ss[tid] = s;
  __syncthreads();
  for (int off = 128; off > 0; off >>= 1) {
    if (tid < off) {
      float m2 = ms[tid + off], s2 = ss[tid + off];
      float m1 = ms[tid], s1 = ss[tid];
      float mm = fmaxf(m1, m2);
      ms[tid] = mm;
      ss[tid] = s1 * __expf(m1 - mm) + s2 * __expf(m2 - mm);
    }
    __syncthreads();
  }
  const float M = ms[0];
  const float inv = 1.f / ss[0];
  half_t* Pr = Pb + (size_t)n * N_NODES;
  for (int c = tid; c < N_NODES; c += 256) {
    const float* Ec = E + c * D_EMB;
    float v = 0.f;
#pragma unroll
    for (int d = 0; d < D_EMB; ++d) v += en[d] * Ec[d];
    v = fmaxf(v, 0.f);
    Pr[c] = (half_t)(__expf(v - M) * inv);
  }
}

// ---------------------------------------------------------------------------
// Build V0 in both layouts (+ X part of Cb in both layouts), fp16.
// ---------------------------------------------------------------------------
__global__ __launch_bounds__(256) void k_build_v0(const float* __restrict__ X,
                                                  const float* __restrict__ H,
                                                  half_t* __restrict__ Vt,
                                                  half_t* __restrict__ Vn,
                                                  half_t* __restrict__ Cbt,
                                                  half_t* __restrict__ Cbn) {
  size_t idx = (size_t)blockIdx.x * 256 + threadIdx.x;
  if (idx >= (size_t)N_NODES * NCOLS) return;
  const int m = (int)(idx / NCOLS);
  const int col = (int)(idx % NCOLS);
  const int b = col / CI;
  const int c = col % CI;
  float v;
  if (c < CIN) v = X[((size_t)b * N_NODES + m) * CIN + c];
  else         v = H[((size_t)b * N_NODES + m) * COUT + (c - CIN)];
  const half_t h = (half_t)v;
  Vn[(size_t)m * NPAD + col] = h;
  Vt[(size_t)col * LDT + m] = h;
  if (c < CIN) {
    Cbn[(size_t)m * NPAD + col] = h;
    Cbt[(size_t)col * LDT + m] = h;
  }
}

// ---------------------------------------------------------------------------
// fp16 MFMA NT-GEMM: C[m][n] = sum_k A[m][k] * Bt[n][k]
// A [4096 x 4096] fp16, Bt [NPAD x LDT] fp16. 128x128 tile, BK=32,
// 4 waves x (4x4 of 16x16x32 MFMA), global_load_lds width-16 staging.
// Dual-store epilogue: Cn[m][n] (NPAD stride) and Ct[n][m] (LDT stride).
// ---------------------------------------------------------------------------
__global__ __launch_bounds__(256) void k_gemm_f16(const half_t* __restrict__ A,
                                                  const half_t* __restrict__ Bt,
                                                  half_t* __restrict__ Cn,
                                                  half_t* __restrict__ Ct) {
  __shared__ half_t As[128 * 32];
  __shared__ half_t Bs[128 * 32];
  const int tid = threadIdx.x;
  const int lane = tid & 63;
  const int wave = tid >> 6;
  const int wm = (wave >> 1) * 64;
  const int wn = (wave & 1) * 64;
  const int rb = blockIdx.y * 128;
  const int cb = blockIdx.x * 128;

  // Staging: wave w's two chunks deposit LDS elements [w*1024, w*1024+1024);
  // lane l -> row (l>>2), k-group (l&3)*8  => element offset l*8 (contiguous).
  const int srow = (lane >> 2);
  const int skg = (lane & 3) * 8;
  const half_t* ga0 = A + (size_t)(rb + wave * 32 + srow) * N_NODES + skg;
  const half_t* ga1 = ga0 + (size_t)16 * N_NODES;
  const half_t* gb0 = Bt + (size_t)(cb + wave * 32 + srow) * LDT + skg;
  const half_t* gb1 = gb0 + (size_t)16 * LDT;
  half_t* lA0 = As + wave * 1024;
  half_t* lA1 = lA0 + 512;
  half_t* lB0 = Bs + wave * 1024;
  half_t* lB1 = lB0 + 512;

  const int fr = lane & 15;            // row within 16-tile
  const int fk = (lane >> 4) * 8;      // k-offset (elements)

  f32x4 acc[4][4] = {};

  for (int k0 = 0; k0 < N_NODES; k0 += 32) {
    __syncthreads();
    gld_lds16(ga0 + k0, lA0);
    gld_lds16(ga1 + k0, lA1);
    gld_lds16(gb0 + k0, lB0);
    gld_lds16(gb1 + k0, lB1);
    __syncthreads();

    f16x8 a[4], b[4];
#pragma unroll
    for (int i = 0; i < 4; ++i)
      a[i] = *(const f16x8*)&As[(wm + i * 16 + fr) * 32 + fk];
#pragma unroll
    for (int j = 0; j < 4; ++j)
      b[j] = *(const f16x8*)&Bs[(wn + j * 16 + fr) * 32 + fk];
#pragma unroll
    for (int i = 0; i < 4; ++i)
#pragma unroll
      for (int j = 0; j < 4; ++j)
        acc[i][j] = __builtin_amdgcn_mfma_f32_16x16x32_f16(a[i], b[j], acc[i][j], 0, 0, 0);
  }

  // Epilogue: C/D layout col = lane&15 (n), row = (lane>>4)*4 + reg (m).
  const int en = lane & 15;
  const int em = (lane >> 4) * 4;
#pragma unroll
  for (int i = 0; i < 4; ++i) {
#pragma unroll
    for (int j = 0; j < 4; ++j) {
      const int m0 = rb + wm + i * 16 + em;
      const int n = cb + wn + j * 16 + en;
      half_t h0 = (half_t)acc[i][j][0];
      half_t h1 = (half_t)acc[i][j][1];
      half_t h2 = (half_t)acc[i][j][2];
      half_t h3 = (half_t)acc[i][j][3];
      struct { half_t a, b, c, d; } t4 = {h0, h1, h2, h3};
      *(decltype(t4)*)&Ct[(size_t)n * LDT + m0] = t4;  // 8B store
      Cn[(size_t)(m0 + 0) * NPAD + n] = h0;            // scalar stores
      Cn[(size_t)(m0 + 1) * NPAD + n] = h1;
      Cn[(size_t)(m0 + 2) * NPAD + n] = h2;
      Cn[(size_t)(m0 + 3) * NPAD + n] = h3;
    }
  }
}

// ---------------------------------------------------------------------------
// Gate transform (fp32 math, fp16 G reads). Block = (node n, chunk of 16 of 128).
// ---------------------------------------------------------------------------
__global__ __launch_bounds__(256, 4) void k_gate(const half_t* __restrict__ Vn,
                                                 const half_t* __restrict__ G1n,
                                                 const half_t* __restrict__ G2n,
                                                 const float* __restrict__ E,
                                                 const float* __restrict__ Wg,
                                                 const float* __restrict__ bg,
                                                 const float* __restrict__ H,
                                                 half_t* __restrict__ Cbn,
                                                 half_t* __restrict__ Cbt,
                                                 float* __restrict__ R) {
  const int n = blockIdx.y;
  const int ch = blockIdx.x;     // 0..7
  const int tid = threadIdx.x;
  __shared__ float En[D_EMB];
  __shared__ float bo[OCH];
  __shared__ __align__(16) float Wch[KSUP * CI * OCH];
  __shared__ float xg[3][NCOLS];

  if (tid < D_EMB) En[tid] = E[n * D_EMB + tid];
  __syncthreads();

  if (tid < OCH) {
    float a = 0.f;
#pragma unroll
    for (int d = 0; d < D_EMB; ++d) a += En[d] * bg[d * 128 + ch * OCH + tid];
    bo[tid] = a;
  }
  for (int idx = tid; idx < KSUP * CI * OCH; idx += 256) {
    const int k = idx / (CI * OCH);
    const int rem = idx - k * (CI * OCH);
    const int i = rem >> 4;
    const int o = rem & (OCH - 1);
    float a = 0.f;
#pragma unroll
    for (int d = 0; d < D_EMB; ++d)
      a += En[d] * Wg[(((size_t)d * KSUP + k) * CI + i) * 128 + ch * OCH + o];
    Wch[idx] = a;
  }
  {
    const half_t* v0r = Vn + (size_t)n * NPAD;
    const half_t* g1r = G1n + (size_t)n * NPAD;
    const half_t* g2r = G2n + (size_t)n * NPAD;
    for (int idx = tid; idx < NCOLS; idx += 256) {
      const float a0 = (float)v0r[idx];
      xg[0][idx] = a0;
      xg[1][idx] = (float)g1r[idx];
      xg[2][idx] = 2.f * (float)g2r[idx] - a0;
    }
  }
  __syncthreads();

  const int b = tid >> 3;          // 0..31
  const int o2 = (tid & 7) * 2;    // 0..14
  float a0 = bo[o2], a1 = bo[o2 + 1];
#pragma unroll 1
  for (int k = 0; k < KSUP; ++k) {
    const float* xr = &xg[k][b * CI];
    const float* wr = &Wch[k * CI * OCH + o2];
#pragma unroll 4
    for (int i = 0; i < CI; ++i) {
      const float xv = xr[i];
      const float2 wv = *(const float2*)&wr[i * OCH];
      a0 += xv * wv.x;
      a1 += xv * wv.y;
    }
  }
  const float s0 = fast_sigmoid(a0);
  const float s1 = fast_sigmoid(a1);
  const int og = ch * OCH + o2;
  if (og < COUT) {  // Z chunk: Cb[., b*CI+CIN+og] = Z * H  (both layouts)
    const float2 h = *(const float2*)&H[((size_t)b * N_NODES + n) * COUT + og];
    const half_t z0 = (half_t)(s0 * h.x);
    const half_t z1 = (half_t)(s1 * h.y);
    const int c0 = b * CI + CIN + og;
    Cbn[(size_t)n * NPAD + c0] = z0;
    Cbn[(size_t)n * NPAD + c0 + 1] = z1;
    Cbt[(size_t)c0 * LDT + n] = z0;
    Cbt[(size_t)(c0 + 1) * LDT + n] = z1;
  } else {          // R chunk (fp32)
    float2 r = {s0, s1};
    *(float2*)&R[((size_t)b * N_NODES + n) * COUT + (og - COUT)] = r;
  }
}

// ---------------------------------------------------------------------------
// Update transform + final gating.
// ---------------------------------------------------------------------------
__global__ __launch_bounds__(256, 4) void k_update(const half_t* __restrict__ Cbn,
                                                   const half_t* __restrict__ G1n,
                                                   const half_t* __restrict__ G2n,
                                                   const float* __restrict__ E,
                                                   const float* __restrict__ Wu,
                                                   const float* __restrict__ bu,
                                                   const float* __restrict__ H,
                                                   const float* __restrict__ R,
                                                   float* __restrict__ Out) {
  const int n = blockIdx.y;
  const int ch = blockIdx.x;     // 0..3
  const int tid = threadIdx.x;
  __shared__ float En[D_EMB];
  __shared__ float bo[OCH];
  __shared__ __align__(16) float Wch[KSUP * CI * OCH];
  __shared__ float xg[3][NCOLS];

  if (tid < D_EMB) En[tid] = E[n * D_EMB + tid];
  __syncthreads();

  if (tid < OCH) {
    float a = 0.f;
#pragma unroll
    for (int d = 0; d < D_EMB; ++d) a += En[d] * bu[d * COUT + ch * OCH + tid];
    bo[tid] = a;
  }
  for (int idx = tid; idx < KSUP * CI * OCH; idx += 256) {
    const int k = idx / (CI * OCH);
    const int rem = idx - k * (CI * OCH);
    const int i = rem >> 4;
    const int o = rem & (OCH - 1);
    float a = 0.f;
#pragma unroll
    for (int d = 0; d < D_EMB; ++d)
      a += En[d] * Wu[(((size_t)d * KSUP + k) * CI + i) * COUT + ch * OCH + o];
    Wch[idx] = a;
  }
  {
    const half_t* v0r = Cbn + (size_t)n * NPAD;
    const half_t* g1r = G1n + (size_t)n * NPAD;
    const half_t* g2r = G2n + (size_t)n * NPAD;
    for (int idx = tid; idx < NCOLS; idx += 256) {
      const float a0 = (float)v0r[idx];
      xg[0][idx] = a0;
      xg[1][idx] = (float)g1r[idx];
      xg[2][idx] = 2.f * (float)g2r[idx] - a0;
    }
  }
  __syncthreads();

  const int b = tid >> 3;
  const int o2 = (tid & 7) * 2;
  float a0 = bo[o2], a1 = bo[o2 + 1];
#pragma unroll 1
  for (int k = 0; k < KSUP; ++k) {
    const float* xr = &xg[k][b * CI];
    const float* wr = &Wch[k * CI * OCH + o2];
#pragma unroll 4
    for (int i = 0; i < CI; ++i) {
      const float xv = xr[i];
      const float2 wv = *(const float2*)&wr[i * OCH];
      a0 += xv * wv.x;
      a1 += xv * wv.y;
    }
  }
  const int og = ch * OCH + o2;
  const size_t base = ((size_t)b * N_NODES + n) * COUT + og;
  const float2 h = *(const float2*)&H[base];
  const float2 r = *(const float2*)&R[base];
  float2 o;
  o.x = r.x * h.x + (1.f - r.x) * fast_tanh(a0);
  o.y = r.y * h.y + (1.f - r.y) * fast_tanh(a1);
  *(float2*)&Out[base] = o;
}

// ---------------------------------------------------------------------------
extern "C" void kernel_launch(void* const* d_in, const int* in_sizes, int n_in,
                              void* d_out, int out_size, void* d_ws, size_t ws_size,
                              hipStream_t stream) {
  const float* X  = (const float*)d_in[0];
  const float* H  = (const float*)d_in[1];
  const float* E  = (const float*)d_in[2];
  const float* Wg = (const float*)d_in[3];
  const float* bg = (const float*)d_in[4];
  const float* Wu = (const float*)d_in[5];
  const float* bu = (const float*)d_in[6];
  float* out = (float*)d_out;

  // Workspace layout: fp16 buffers then fp32 R. Total ~210 MB.
  const size_t SZ_P = (size_t)N_NODES * N_NODES;   // 16,777,216 elems
  const size_t SZ_M = (size_t)NPAD * LDT;          //  8,912,896 elems
  half_t* Pb  = (half_t*)d_ws;
  half_t* Vt  = Pb + SZ_P;
  half_t* Vn  = Vt + SZ_M;
  half_t* G1t = Vn + SZ_M;
  half_t* G1n = G1t + SZ_M;
  half_t* G2t = G1n + SZ_M;
  half_t* G2n = G2t + SZ_M;
  half_t* Cbt = G2n + SZ_M;
  half_t* Cbn = Cbt + SZ_M;
  float*    R = (float*)(Cbn + SZ_M);              // 8,388,608 floats

  // 1. adjacency (fp16)
  k_softmax_p<<<N_NODES, 256, 0, stream>>>(E, Pb);
  // 2. V0 = concat(X,H), both layouts (+ X part of Cb)
  {
    const size_t tot = (size_t)N_NODES * NCOLS;
    k_build_v0<<<(int)((tot + 255) / 256), 256, 0, stream>>>(X, H, Vt, Vn, Cbt, Cbn);
  }
  dim3 gg(NPAD / 128, N_NODES / 128);
  // 3. gate propagation: G1 = P V0, G2 = P G1
  k_gemm_f16<<<gg, 256, 0, stream>>>(Pb, Vt, G1n, G1t);
  k_gemm_f16<<<gg, 256, 0, stream>>>(Pb, G1t, G2n, G2t);
  // 4. gate transform -> Cb (Z*H part, both layouts), R
  k_gate<<<dim3(128 / OCH, N_NODES), 256, 0, stream>>>(Vn, G1n, G2n, E, Wg, bg, H, Cbn, Cbt, R);
  // 5. update propagation: G1 = P C, G2 = P G1
  k_gemm_f16<<<gg, 256, 0, stream>>>(Pb, Cbt, G1n, G1t);
  k_gemm_f16<<<gg, 256, 0, stream>>>(Pb, G1t, G2n, G2t);
  // 6. update transform + final gating -> out
  k_update<<<dim3(COUT / OCH, N_NODES), 256, 0, stream>>>(Cbn, G1n, G2n, E, Wu, bu, H, R, out);
}